// Round 16
// baseline (94.473 us; speedup 1.0000x reference)
//
#include <hip/hip_runtime.h>
#include <hip/hip_bf16.h>

// BERT self-attention, B=8 S=1024 D=768 H=12 DH=64, fp32 in/out.
// (1) proj v2 (R12 verbatim): BM=64 BN=128, reg-prefetch + dbuf LDS ->
//     mixed + mixedT (per-head [d][tau(t)]).
// (2) attn v5: 128 thr = 2 waves x 64 q-rows (two 32-row q-sets per wave).
//     Each K/V frag LDS read feeds TWO MFMAs -> LDS-read per FLOP halved.
//     32x32x16 swapped-QK, fixed-max softmax, in-reg row-sum, dbuf KV.

#define D_MODEL 768
#define SEQ     1024
#define NHEAD   12
#define DHEAD   64
#define BATCH   8
#define QB      128
#define LOG2E   1.44269504088896f
#define FMLOG   28.8539008178f        /* 20 * log2(e) */
#define SCLC    (0.125f * LOG2E)

typedef __attribute__((ext_vector_type(8)))  short bf16x8;
typedef __attribute__((ext_vector_type(4)))  short short4v;
typedef __attribute__((ext_vector_type(4)))  float f32x4;
typedef __attribute__((ext_vector_type(16))) float f32x16;

__device__ __forceinline__ unsigned short f2bf(float f) {
  __hip_bfloat16 h = __float2bfloat16(f);
  return *reinterpret_cast<unsigned short*>(&h);
}

__device__ __forceinline__ float fexp2(float x) {
#if __has_builtin(__builtin_amdgcn_exp2f)
  return __builtin_amdgcn_exp2f(x);
#else
  return exp2f(x);
#endif
}

// 64-wide bf16 tile: elem-index XOR swizzle (16B granule x row)
__device__ __forceinline__ int lswz(int r, int c) {
  return (r << 6) + (c ^ ((r & 7) << 3));
}
// swap bits 2<->3 of a t-index (the mixedT column permutation)
__device__ __forceinline__ int tau(int t) {
  return (t & ~0xC) | ((t & 8) >> 1) | ((t & 4) << 1);
}

// ---------------------------------------------------------------------------
// Projection GEMM v2 (R12 verbatim): mixed = bf16(X @ W^T + b);
// mixedT = [b][d][tau(t)].  BM=64 BN=128 BK=32; prefetch + dbuf.
// ---------------------------------------------------------------------------
template<bool WRITE_T>
__global__ __launch_bounds__(256) void proj_kernel(
    const float* __restrict__ X, const float* __restrict__ W,
    const float* __restrict__ bias, unsigned short* __restrict__ mixed,
    unsigned short* __restrict__ mixedT)
{
  __shared__ unsigned short As[2][64 * 40];    //  10 KB
  __shared__ unsigned short Bs[2][128 * 40];   //  20 KB

  const int tid = threadIdx.x;
  const int l   = tid & 63;
  const int w   = tid >> 6;
  const int m0  = blockIdx.x * 64;
  const int n0  = blockIdx.y * 128;
  const int wm  = (w >> 1) * 32;
  const int wn  = (w & 1) * 64;
  const int lr  = l & 15;
  const int g   = l >> 4;
  const int lk  = g * 8;

  const int ar = tid >> 2;            // A row 0..63
  const int ac = (tid & 3) * 8;       // col granule

  f32x4 a0, a1, b0[2], b1[2];
  auto loadSlab = [&](int k0) {
    const float* pa = &X[(size_t)(m0 + ar) * D_MODEL + k0 + ac];
    a0 = *(const f32x4*)pa;
    a1 = *(const f32x4*)(pa + 4);
    #pragma unroll
    for (int p = 0; p < 2; ++p) {
      const float* pb = &W[(size_t)(n0 + ar + p * 64) * D_MODEL + k0 + ac];
      b0[p] = *(const f32x4*)pb;
      b1[p] = *(const f32x4*)(pb + 4);
    }
  };
  auto stageSlab = [&](int bb) {
    bf16x8 av;
    #pragma unroll
    for (int jj = 0; jj < 4; ++jj) {
      av[jj]     = (short)f2bf(a0[jj]);
      av[4 + jj] = (short)f2bf(a1[jj]);
    }
    *(bf16x8*)&As[bb][ar * 40 + ac] = av;
    #pragma unroll
    for (int p = 0; p < 2; ++p) {
      bf16x8 bv;
      #pragma unroll
      for (int jj = 0; jj < 4; ++jj) {
        bv[jj]     = (short)f2bf(b0[p][jj]);
        bv[4 + jj] = (short)f2bf(b1[p][jj]);
      }
      *(bf16x8*)&Bs[bb][(ar + p * 64) * 40 + ac] = bv;
    }
  };

  f32x4 acc[2][4] = {};

  loadSlab(0);
  stageSlab(0);
  __syncthreads();

  int cur = 0;
  for (int k0 = 0; k0 < D_MODEL; k0 += 32) {
    const bool more = (k0 + 32 < D_MODEL);
    if (more) loadSlab(k0 + 32);

    bf16x8 af[2], bfr[4];
    #pragma unroll
    for (int am = 0; am < 2; ++am)
      af[am]  = *(const bf16x8*)&As[cur][(wm + am * 16 + lr) * 40 + lk];
    #pragma unroll
    for (int bn = 0; bn < 4; ++bn)
      bfr[bn] = *(const bf16x8*)&Bs[cur][(wn + bn * 16 + lr) * 40 + lk];

    #pragma unroll
    for (int am = 0; am < 2; ++am)
      #pragma unroll
      for (int bn = 0; bn < 4; ++bn)
        acc[am][bn] = __builtin_amdgcn_mfma_f32_16x16x32_bf16(
            af[am], bfr[bn], acc[am][bn], 0, 0, 0);

    if (more) {
      stageSlab(cur ^ 1);
      __syncthreads();
    }
    cur ^= 1;
  }

  const int orow = g * 4;
  const int bT   = m0 >> 10;
  const int tl0  = (m0 & 1023) + wm + orow;
  #pragma unroll
  for (int bn = 0; bn < 4; ++bn) {
    int   col  = n0 + wn + bn * 16 + lr;
    float bcol = bias[col];
    size_t tbase = ((size_t)bT * D_MODEL + col) * SEQ;
    #pragma unroll
    for (int am = 0; am < 2; ++am) {
      short4v pk;
      #pragma unroll
      for (int i = 0; i < 4; ++i) {
        float v = acc[am][bn][i] + bcol;
        unsigned short hv = f2bf(v);
        mixed[(size_t)(m0 + wm + am * 16 + orow + i) * D_MODEL + col] = hv;
        pk[i] = (short)hv;
      }
      if (WRITE_T)
        *(short4v*)&mixedT[tbase + tau(tl0 + am * 16)] = pk;
    }
  }
}

// ---------------------------------------------------------------------------
// attn v5: 128 thr = 2 waves; each wave owns 64 q-rows as 2 q-sets of 32.
// Each kf/vf LDS read feeds both q-sets (2 MFMA per read).
// ---------------------------------------------------------------------------
__global__ __launch_bounds__(128) void attn_kernel(
    const unsigned short* __restrict__ mixed,
    const unsigned short* __restrict__ mixedT,
    const float* __restrict__ mask, float* __restrict__ out)
{
  __shared__ unsigned short Kbuf[2][4096];  // 16 KB; Q bounce at init
  __shared__ unsigned short Vbuf[2][4096];  // 16 KB
  __shared__ float maskE[SEQ];              //  4 KB
  __shared__ float lb[128];                 // 512 B
  __shared__ int   mflag;

  const int tid = threadIdx.x;
  const int l   = tid & 63;
  const int w   = tid >> 6;            // 0..1
  const int l31 = l & 31;
  const int lh  = l >> 5;
  const int h4  = lh * 4;
  const int h8  = lh * 8;

  // T1: XCD-grouped decode — all 8 q-tiles of one (b,h) share id mod 8.
  const int id  = blockIdx.x;          // 0..767
  const int xcd = id & 7;
  const int j   = id >> 3;             // 0..95
  const int pr  = xcd * 12 + (j >> 3); // (b,head), bijective over 96
  const int q0  = (j & 7) * QB;
  const int hd  = pr % NHEAD;
  const int b   = pr / NHEAD;

  const size_t base  = ((size_t)b * SEQ) * D_MODEL + hd * DHEAD;
  const size_t baseT = ((size_t)b * D_MODEL + hd * DHEAD) * SEQ;

  const int r0 = tid >> 3;             // 0..15 staging row (+p*16)
  const int sc = (tid & 7) * 8;        // staging col granule

  // ---- mask scan + exp2-domain fold ----
  if (tid == 0) mflag = 0;
  __syncthreads();
  {
    f32x4 m0 = *(const f32x4*)&mask[(size_t)b * SEQ + tid * 8];
    f32x4 m1 = *(const f32x4*)&mask[(size_t)b * SEQ + tid * 8 + 4];
    #pragma unroll
    for (int jj = 0; jj < 4; ++jj) {
      maskE[tid * 8 + jj]     = fmaf(m0[jj], LOG2E, -FMLOG);
      maskE[tid * 8 + 4 + jj] = fmaf(m1[jj], LOG2E, -FMLOG);
    }
    if (m0[0] != 0.f || m0[1] != 0.f || m0[2] != 0.f || m0[3] != 0.f ||
        m1[0] != 0.f || m1[1] != 0.f || m1[2] != 0.f || m1[3] != 0.f)
      mflag = 1;
  }

  // ---- stage Q (128x64) into Kbuf flat (16 KB), hoist frags ----
  unsigned short* QQ = &Kbuf[0][0];
  #pragma unroll
  for (int pp = 0; pp < 8; ++pp) {
    int g   = tid + pp * 128;
    int row = g >> 3;
    int c   = (g & 7) * 8;
    *(bf16x8*)&QQ[lswz(row, c)] =
        *(const bf16x8*)&mixed[base + (size_t)(q0 + row) * D_MODEL + c];
  }
  __syncthreads();

  const bool hm = (mflag != 0);
  bf16x8 qfA[4], qfB[4];
  #pragma unroll
  for (int db = 0; db < 4; ++db) {
    qfA[db] = *(const bf16x8*)&QQ[lswz(w * 64 + l31,      db * 16 + h8)];
    qfB[db] = *(const bf16x8*)&QQ[lswz(w * 64 + 32 + l31, db * 16 + h8)];
  }
  __syncthreads();                     // Q reads done before kv0 overwrites

  // ---- staging: 4 K + 4 V granules per thread per tile ----
  bf16x8 kr[4], vr[4];
  auto loadKV = [&](int tt) {
    #pragma unroll
    for (int p = 0; p < 4; ++p) {
      kr[p] = *(const bf16x8*)&mixed[base + (size_t)(tt + r0 + p * 16) * D_MODEL + sc];
      vr[p] = *(const bf16x8*)&mixedT[baseT + (size_t)(r0 + p * 16) * SEQ + tt + sc];
    }
  };
  auto stageKV = [&](unsigned short* Kd, unsigned short* Vd) {
    #pragma unroll
    for (int p = 0; p < 4; ++p) {
      *(bf16x8*)&Kd[lswz(r0 + p * 16, sc)] = kr[p];
      *(bf16x8*)&Vd[lswz(r0 + p * 16, sc)] = vr[p];
    }
  };

  unsigned short* Kc = &Kbuf[0][0];
  unsigned short* Kn = &Kbuf[1][0];
  unsigned short* Vc = &Vbuf[0][0];
  unsigned short* Vn = &Vbuf[1][0];

  loadKV(0);
  stageKV(Kc, Vc);
  __syncthreads();

  f32x16 c0A = {}, c1A = {}, c0B = {}, c1B = {};
  float lsA = 0.f, lsB = 0.f;

  for (int t0 = 0; t0 < SEQ; t0 += 64) {
    const bool more = (t0 + 64 < SEQ);

    #pragma unroll
    for (int sub = 0; sub < 2; ++sub) {
      const int sr = sub * 32;

      // ---- QK: each kf read feeds both q-sets (4 reads -> 8 MFMA) ----
      f32x16 sA = {}, sB = {};
      #pragma unroll
      for (int db = 0; db < 4; ++db) {
        bf16x8 kf = *(const bf16x8*)&Kc[lswz(sr + l31, db * 16 + h8)];
        sA = __builtin_amdgcn_mfma_f32_32x32x16_bf16(kf, qfA[db], sA, 0, 0, 0);
        sB = __builtin_amdgcn_mfma_f32_32x32x16_bf16(kf, qfB[db], sB, 0, 0, 0);
      }

      // ---- softmax-lite per q-set (sequential: one p[16] live) ----
      bf16x8 paA[2], paB[2];
      {
        float p[16];
        if (hm) {
          #pragma unroll
          for (int r = 0; r < 16; ++r) {
            int kvr = (r & 3) + 8 * (r >> 2) + h4;
            p[r] = fexp2(fmaf(sA[r], SCLC, maskE[t0 + sr + kvr]));
            lsA += p[r];
          }
        } else {
          #pragma unroll
          for (int r = 0; r < 16; ++r) {
            p[r] = fexp2(fmaf(sA[r], SCLC, -FMLOG));
            lsA += p[r];
          }
        }
        #pragma unroll
        for (int f = 0; f < 2; ++f)
          #pragma unroll
          for (int jj = 0; jj < 8; ++jj) paA[f][jj] = (short)f2bf(p[8 * f + jj]);
      }
      {
        float p[16];
        if (hm) {
          #pragma unroll
          for (int r = 0; r < 16; ++r) {
            int kvr = (r & 3) + 8 * (r >> 2) + h4;
            p[r] = fexp2(fmaf(sB[r], SCLC, maskE[t0 + sr + kvr]));
            lsB += p[r];
          }
        } else {
          #pragma unroll
          for (int r = 0; r < 16; ++r) {
            p[r] = fexp2(fmaf(sB[r], SCLC, -FMLOG));
            lsB += p[r];
          }
        }
        #pragma unroll
        for (int f = 0; f < 2; ++f)
          #pragma unroll
          for (int jj = 0; jj < 8; ++jj) paB[f][jj] = (short)f2bf(p[8 * f + jj]);
      }

      // ---- prefetch next tile between subtiles (regs live during sub 1
      //      and PV only; avoids overlapping the sA/sB peak of sub 0) ----
      if (sub == 0 && more) loadKV(t0 + 64);

      // ---- PV: each vf read feeds both q-sets (4 reads -> 8 MFMA) ----
      #pragma unroll
      for (int f = 0; f < 2; ++f) {
        const int cc = sr + f * 16 + h8;
        bf16x8 v0 = *(const bf16x8*)&Vc[lswz(l31, cc)];
        bf16x8 v1 = *(const bf16x8*)&Vc[lswz(32 + l31, cc)];
        c0A = __builtin_amdgcn_mfma_f32_32x32x16_bf16(paA[f], v0, c0A, 0, 0, 0);
        c1A = __builtin_amdgcn_mfma_f32_32x32x16_bf16(paA[f], v1, c1A, 0, 0, 0);
        c0B = __builtin_amdgcn_mfma_f32_32x32x16_bf16(paB[f], v0, c0B, 0, 0, 0);
        c1B = __builtin_amdgcn_mfma_f32_32x32x16_bf16(paB[f], v1, c1B, 0, 0, 0);
      }
    }

    if (more) {
      stageKV(Kn, Vn);
      __syncthreads();
    }
    unsigned short* t;
    t = Kc; Kc = Kn; Kn = t;
    t = Vc; Vc = Vn; Vn = t;
  }

  // ---- finalize l per q-set: cross-half add, bounce via LDS ----
  float ltA = lsA + __shfl_xor(lsA, 32);
  float ltB = lsB + __shfl_xor(lsB, 32);
  if (lh == 0) {
    lb[w * 64 + l31]      = ltA;
    lb[w * 64 + 32 + l31] = ltB;
  }
  // same-wave LDS reads below; compiler inserts the wait

  #pragma unroll
  for (int r = 0; r < 16; ++r) {
    int qr = (r & 3) + 8 * (r >> 2) + h4;
    int rowA = q0 + w * 64 + qr;
    float liA = __builtin_amdgcn_rcpf(lb[w * 64 + qr]);
    float* oA = &out[((size_t)b * SEQ + rowA) * D_MODEL + hd * DHEAD];
    oA[l31]      = c0A[r] * liA;
    oA[32 + l31] = c1A[r] * liA;

    int rowB = rowA + 32;
    float liB = __builtin_amdgcn_rcpf(lb[w * 64 + 32 + qr]);
    float* oB = &out[((size_t)b * SEQ + rowB) * D_MODEL + hd * DHEAD];
    oB[l31]      = c0B[r] * liB;
    oB[32 + l31] = c1B[r] * liB;
  }
}

// ---------------------------------------------------------------------------
extern "C" void kernel_launch(void* const* d_in, const int* in_sizes, int n_in,
                              void* d_out, int out_size, void* d_ws, size_t ws_size,
                              hipStream_t stream) {
  const float* x    = (const float*)d_in[0];
  const float* mask = (const float*)d_in[1];
  const float* W    = (const float*)d_in[2];
  const float* bias = (const float*)d_in[3];
  float* out        = (float*)d_out;

  const size_t NM = (size_t)8192 * D_MODEL;
  unsigned short* mixed  = (unsigned short*)d_ws;          // 12.58 MB
  unsigned short* mixedT = mixed + NM;                      // 12.58 MB

  dim3 gp(8192 / 64, D_MODEL / 128);                // (128, 6) = 768 blocks
  const int nblk = (SEQ / QB) * NHEAD * BATCH;      // 768 = 8 * 96

  proj_kernel<true><<<gp, 256, 0, stream>>>(x, W, bias, mixed, mixedT);
  attn_kernel<<<nblk, 128, 0, stream>>>(mixed, mixedT, mask, out);
}

// Round 17
// 66.999 us; speedup vs baseline: 1.4101x; 1.4101x over previous
//
#include <hip/hip_runtime.h>
#include <hip/hip_bf16.h>

// BERT self-attention, B=8 S=1024 D=768 H=12 DH=64, fp32 in/out.
// R12 configuration restored (best measured: 67.4 us) + T5 setprio on attn
// MFMA clusters.
// (1) proj v2: BM=64 BN=128 BK=32, reg-prefetch + dbuf LDS (1 barrier/step)
//     -> mixed + mixedT (per-head [d][tau(t)]).
// (2) attn: 32x32x16 swapped-QK MFMA, 4 waves x 32 q-rows (QB=128), 32-row
//     kv subtiles, fixed-max softmax, in-reg row-sum, ptr-swap dbuf, T1, T14.

#define D_MODEL 768
#define SEQ     1024
#define NHEAD   12
#define DHEAD   64
#define BATCH   8
#define QB      128
#define LOG2E   1.44269504088896f
#define FMLOG   28.8539008178f        /* 20 * log2(e) */
#define SCLC    (0.125f * LOG2E)

typedef __attribute__((ext_vector_type(8)))  short bf16x8;
typedef __attribute__((ext_vector_type(4)))  short short4v;
typedef __attribute__((ext_vector_type(4)))  float f32x4;
typedef __attribute__((ext_vector_type(16))) float f32x16;

__device__ __forceinline__ unsigned short f2bf(float f) {
  __hip_bfloat16 h = __float2bfloat16(f);
  return *reinterpret_cast<unsigned short*>(&h);
}

__device__ __forceinline__ float fexp2(float x) {
#if __has_builtin(__builtin_amdgcn_exp2f)
  return __builtin_amdgcn_exp2f(x);
#else
  return exp2f(x);
#endif
}

// 64-wide bf16 tile: elem-index XOR swizzle (16B granule x row)
__device__ __forceinline__ int lswz(int r, int c) {
  return (r << 6) + (c ^ ((r & 7) << 3));
}
// swap bits 2<->3 of a t-index (the mixedT column permutation)
__device__ __forceinline__ int tau(int t) {
  return (t & ~0xC) | ((t & 8) >> 1) | ((t & 4) << 1);
}

// ---------------------------------------------------------------------------
// Projection GEMM v2 (R12 verbatim): mixed = bf16(X @ W^T + b);
// mixedT = [b][d][tau(t)].  BM=64 BN=128 BK=32; prefetch + dbuf.
// ---------------------------------------------------------------------------
template<bool WRITE_T>
__global__ __launch_bounds__(256) void proj_kernel(
    const float* __restrict__ X, const float* __restrict__ W,
    const float* __restrict__ bias, unsigned short* __restrict__ mixed,
    unsigned short* __restrict__ mixedT)
{
  __shared__ unsigned short As[2][64 * 40];    //  10 KB
  __shared__ unsigned short Bs[2][128 * 40];   //  20 KB

  const int tid = threadIdx.x;
  const int l   = tid & 63;
  const int w   = tid >> 6;
  const int m0  = blockIdx.x * 64;
  const int n0  = blockIdx.y * 128;
  const int wm  = (w >> 1) * 32;
  const int wn  = (w & 1) * 64;
  const int lr  = l & 15;
  const int g   = l >> 4;
  const int lk  = g * 8;

  const int ar = tid >> 2;            // A row 0..63
  const int ac = (tid & 3) * 8;       // col granule

  f32x4 a0, a1, b0[2], b1[2];
  auto loadSlab = [&](int k0) {
    const float* pa = &X[(size_t)(m0 + ar) * D_MODEL + k0 + ac];
    a0 = *(const f32x4*)pa;
    a1 = *(const f32x4*)(pa + 4);
    #pragma unroll
    for (int p = 0; p < 2; ++p) {
      const float* pb = &W[(size_t)(n0 + ar + p * 64) * D_MODEL + k0 + ac];
      b0[p] = *(const f32x4*)pb;
      b1[p] = *(const f32x4*)(pb + 4);
    }
  };
  auto stageSlab = [&](int bb) {
    bf16x8 av;
    #pragma unroll
    for (int jj = 0; jj < 4; ++jj) {
      av[jj]     = (short)f2bf(a0[jj]);
      av[4 + jj] = (short)f2bf(a1[jj]);
    }
    *(bf16x8*)&As[bb][ar * 40 + ac] = av;
    #pragma unroll
    for (int p = 0; p < 2; ++p) {
      bf16x8 bv;
      #pragma unroll
      for (int jj = 0; jj < 4; ++jj) {
        bv[jj]     = (short)f2bf(b0[p][jj]);
        bv[4 + jj] = (short)f2bf(b1[p][jj]);
      }
      *(bf16x8*)&Bs[bb][(ar + p * 64) * 40 + ac] = bv;
    }
  };

  f32x4 acc[2][4] = {};

  loadSlab(0);
  stageSlab(0);
  __syncthreads();

  int cur = 0;
  for (int k0 = 0; k0 < D_MODEL; k0 += 32) {
    const bool more = (k0 + 32 < D_MODEL);
    if (more) loadSlab(k0 + 32);       // T14: issue next slab's loads early

    bf16x8 af[2], bfr[4];
    #pragma unroll
    for (int am = 0; am < 2; ++am)
      af[am]  = *(const bf16x8*)&As[cur][(wm + am * 16 + lr) * 40 + lk];
    #pragma unroll
    for (int bn = 0; bn < 4; ++bn)
      bfr[bn] = *(const bf16x8*)&Bs[cur][(wn + bn * 16 + lr) * 40 + lk];

    #pragma unroll
    for (int am = 0; am < 2; ++am)
      #pragma unroll
      for (int bn = 0; bn < 4; ++bn)
        acc[am][bn] = __builtin_amdgcn_mfma_f32_16x16x32_bf16(
            af[am], bfr[bn], acc[am][bn], 0, 0, 0);

    if (more) {
      stageSlab(cur ^ 1);
      __syncthreads();
    }
    cur ^= 1;
  }

  const int orow = g * 4;
  const int bT   = m0 >> 10;
  const int tl0  = (m0 & 1023) + wm + orow;
  #pragma unroll
  for (int bn = 0; bn < 4; ++bn) {
    int   col  = n0 + wn + bn * 16 + lr;
    float bcol = bias[col];
    size_t tbase = ((size_t)bT * D_MODEL + col) * SEQ;
    #pragma unroll
    for (int am = 0; am < 2; ++am) {
      short4v pk;
      #pragma unroll
      for (int i = 0; i < 4; ++i) {
        float v = acc[am][bn][i] + bcol;
        unsigned short hv = f2bf(v);
        mixed[(size_t)(m0 + wm + am * 16 + orow + i) * D_MODEL + col] = hv;
        pk[i] = (short)hv;
      }
      if (WRITE_T)
        *(short4v*)&mixedT[tbase + tau(tl0 + am * 16)] = pk;
    }
  }
}

// ---------------------------------------------------------------------------
// Fused attention (R12 structure + T5 setprio): 256 thr = 4 waves x 32
// q-rows; 32-row kv subtiles; QB=128.
// ---------------------------------------------------------------------------
__global__ __launch_bounds__(256, 4) void attn_kernel(
    const unsigned short* __restrict__ mixed,
    const unsigned short* __restrict__ mixedT,
    const float* __restrict__ mask, float* __restrict__ out)
{
  __shared__ unsigned short Xbuf[2][4096];  // 16 KB: K rows [t][d]; Q at init
  __shared__ unsigned short Tbuf[2][4096];  // 16 KB: V^T rows [d][t']
  __shared__ float maskE[SEQ];              //  4 KB
  __shared__ float lb[128];                 // 512 B
  __shared__ int   mflag;

  const int tid = threadIdx.x;
  const int l   = tid & 63;
  const int wq  = tid >> 6;            // 0..3
  const int l31 = l & 31;
  const int lh  = l >> 5;              // lane half
  const int h4  = lh * 4;
  const int h8  = lh * 8;

  // T1: XCD-grouped decode — all 8 q-tiles of one (b,h) share id mod 8.
  const int id  = blockIdx.x;          // 0..767
  const int xcd = id & 7;
  const int j   = id >> 3;             // 0..95
  const int pr  = xcd * 12 + (j >> 3); // (b,head), bijective over 96
  const int q0  = (j & 7) * QB;
  const int hd  = pr % NHEAD;
  const int b   = pr / NHEAD;

  const size_t base  = ((size_t)b * SEQ) * D_MODEL + hd * DHEAD;
  const size_t baseT = ((size_t)b * D_MODEL + hd * DHEAD) * SEQ;

  const int r0 = tid >> 3;             // 0..31 staging row
  const int sc = (tid & 7) * 8;        // staging col (granule)

  // ---- mask scan + exp2-domain fold ----
  if (tid == 0) mflag = 0;
  __syncthreads();
  {
    f32x4 mv = *(const f32x4*)&mask[(size_t)b * SEQ + tid * 4];
    #pragma unroll
    for (int jj = 0; jj < 4; ++jj)
      maskE[tid * 4 + jj] = fmaf(mv[jj], LOG2E, -FMLOG);
    if (mv[0] != 0.f || mv[1] != 0.f || mv[2] != 0.f || mv[3] != 0.f)
      mflag = 1;
  }

  // ---- stage Q (128x64) into Xbuf flat region ----
  unsigned short* QQ = &Xbuf[0][0];
  #pragma unroll
  for (int pp = 0; pp < 4; ++pp) {
    int g   = tid + pp * 256;
    int row = g >> 3;
    int c   = (g & 7) * 8;
    *(bf16x8*)&QQ[lswz(row, c)] =
        *(const bf16x8*)&mixed[base + (size_t)(q0 + row) * D_MODEL + c];
  }
  __syncthreads();

  const bool hm = (mflag != 0);
  bf16x8 qf[4];                        // Q B-frags, hoisted
  #pragma unroll
  for (int db = 0; db < 4; ++db)
    qf[db] = *(const bf16x8*)&QQ[lswz(wq * 32 + l31, db * 16 + h8)];
  __syncthreads();                     // Q reads done before kv0 overwrites

  // ---- staging helpers ----
  bf16x8 k0r, k1r, t0r, t1r;
  auto loadKV = [&](int tt) {
    k0r = *(const bf16x8*)&mixed[base + (size_t)(tt + r0) * D_MODEL + sc];
    k1r = *(const bf16x8*)&mixed[base + (size_t)(tt + r0 + 32) * D_MODEL + sc];
    t0r = *(const bf16x8*)&mixedT[baseT + (size_t)r0 * SEQ + tt + sc];
    t1r = *(const bf16x8*)&mixedT[baseT + (size_t)(r0 + 32) * SEQ + tt + sc];
  };
  auto stageKV = [&](unsigned short* Xd, unsigned short* Td) {
    *(bf16x8*)&Xd[lswz(r0, sc)]      = k0r;
    *(bf16x8*)&Xd[lswz(r0 + 32, sc)] = k1r;
    *(bf16x8*)&Td[lswz(r0, sc)]      = t0r;
    *(bf16x8*)&Td[lswz(r0 + 32, sc)] = t1r;
  };

  unsigned short* Xc = &Xbuf[0][0];
  unsigned short* Xn = &Xbuf[1][0];
  unsigned short* Tc = &Tbuf[0][0];
  unsigned short* Tn = &Tbuf[1][0];

  loadKV(0);
  stageKV(Xc, Tc);
  __syncthreads();

  f32x16 c0 = {}, c1 = {};
  float lsum = 0.f;

  for (int t0 = 0; t0 < SEQ; t0 += 64) {
    const bool more = (t0 + 64 < SEQ);
    if (more) loadKV(t0 + 64);         // T14: issue next tile's loads early

    // ---- two 32-row kv subtiles; only one s-acc (16 regs) live ----
    #pragma unroll
    for (int sub = 0; sub < 2; ++sub) {
      const int sr = sub * 32;

      // S^T subtile = K[sr..sr+31] @ Q^T : 4 MFMA (T5: boosted)
      f32x16 s = {};
      __builtin_amdgcn_s_setprio(1);
      #pragma unroll
      for (int db = 0; db < 4; ++db) {
        bf16x8 kf = *(const bf16x8*)&Xc[lswz(sr + l31, db * 16 + h8)];
        s = __builtin_amdgcn_mfma_f32_32x32x16_bf16(kf, qf[db], s, 0, 0, 0);
      }
      __builtin_amdgcn_s_setprio(0);

      // softmax-lite (fixed max) -> p[16], row-sum in-reg
      float p[16];
      if (hm) {
        #pragma unroll
        for (int r = 0; r < 16; ++r) {
          int kvr = (r & 3) + 8 * (r >> 2) + h4;
          p[r] = fexp2(fmaf(s[r], SCLC, maskE[t0 + sr + kvr]));
          lsum += p[r];
        }
      } else {
        #pragma unroll
        for (int r = 0; r < 16; ++r) {
          p[r] = fexp2(fmaf(s[r], SCLC, -FMLOG));
          lsum += p[r];
        }
      }

      // pack A-frags and PV: 4 MFMA (T5: boosted)
      __builtin_amdgcn_s_setprio(1);
      #pragma unroll
      for (int f = 0; f < 2; ++f) {
        bf16x8 pa;
        #pragma unroll
        for (int jj = 0; jj < 8; ++jj) pa[jj] = (short)f2bf(p[8 * f + jj]);
        const int cc = sr + f * 16 + h8;
        bf16x8 v0 = *(const bf16x8*)&Tc[lswz(l31, cc)];
        bf16x8 v1 = *(const bf16x8*)&Tc[lswz(32 + l31, cc)];
        c0 = __builtin_amdgcn_mfma_f32_32x32x16_bf16(pa, v0, c0, 0, 0, 0);
        c1 = __builtin_amdgcn_mfma_f32_32x32x16_bf16(pa, v1, c1, 0, 0, 0);
      }
      __builtin_amdgcn_s_setprio(0);
    }

    if (more) {
      stageKV(Xn, Tn);
      __syncthreads();
    }
    unsigned short* t;
    t = Xc; Xc = Xn; Xn = t;
    t = Tc; Tc = Tn; Tn = t;
  }

  // ---- finalize l: cross-half add, bounce to C-layout via LDS ----
  float l_tot = lsum + __shfl_xor(lsum, 32);
  if (lh == 0) lb[wq * 32 + l31] = l_tot;
  // same-wave LDS read below; compiler inserts the wait

  #pragma unroll
  for (int r = 0; r < 16; ++r) {
    int qr = (r & 3) + 8 * (r >> 2) + h4;
    float linv = __builtin_amdgcn_rcpf(lb[wq * 32 + qr]);
    int row = q0 + wq * 32 + qr;
    float* orow = &out[((size_t)b * SEQ + row) * D_MODEL + hd * DHEAD];
    orow[l31]      = c0[r] * linv;
    orow[32 + l31] = c1[r] * linv;
  }
}

// ---------------------------------------------------------------------------
extern "C" void kernel_launch(void* const* d_in, const int* in_sizes, int n_in,
                              void* d_out, int out_size, void* d_ws, size_t ws_size,
                              hipStream_t stream) {
  const float* x    = (const float*)d_in[0];
  const float* mask = (const float*)d_in[1];
  const float* W    = (const float*)d_in[2];
  const float* bias = (const float*)d_in[3];
  float* out        = (float*)d_out;

  const size_t NM = (size_t)8192 * D_MODEL;
  unsigned short* mixed  = (unsigned short*)d_ws;          // 12.58 MB
  unsigned short* mixedT = mixed + NM;                      // 12.58 MB

  dim3 gp(8192 / 64, D_MODEL / 128);                // (128, 6) = 768 blocks
  const int nblk = (SEQ / QB) * NHEAD * BATCH;      // 768 = 8 * 96

  proj_kernel<true><<<gp, 256, 0, stream>>>(x, W, bias, mixed, mixedT);
  attn_kernel<<<nblk, 256, 0, stream>>>(mixed, mixedT, mask, out);
}